// Round 1
// baseline (120.256 us; speedup 1.0000x reference)
//
#include <hip/hip_runtime.h>
#include <math.h>

#define NC 14        // classes / centroids
#define BB 32        // batch
#define NN 16384     // subsampled points per batch
#define PP 4096      // origin points per batch

// Kernel A: per-batch centroids (from origin xyz + target) -> ws,
// plus fused chamfer l1/l2 + separation losses -> atomicAdd(out).
__global__ void centroids_chamfer_kernel(const float* __restrict__ origin, // [B,9,P]
                                         const int*   __restrict__ target, // [B,P]
                                         const float* __restrict__ cpred,  // [B,3,C]
                                         float* __restrict__ cent_ws,      // [B,C,3]
                                         float* __restrict__ out) {
    const int b   = blockIdx.x;
    const int tid = threadIdx.x;

    __shared__ float s_sum[NC][3];
    __shared__ float s_cnt[NC];
    __shared__ float s_cent[NC][3];
    __shared__ float s_D[NC][NC];
    __shared__ float s_loss;

    if (tid < NC)        s_cnt[tid] = 0.f;
    if (tid < NC * 3)    ((float*)s_sum)[tid] = 0.f;
    if (tid == 0)        s_loss = 0.f;
    __syncthreads();

    const float* ob = origin + (size_t)b * 9 * PP;
    const int*   tb = target + (size_t)b * PP;

    for (int p = tid; p < PP; p += blockDim.x) {
        int t = tb[p];
        float x = ob[p], y = ob[PP + p], z = ob[2 * PP + p];
        atomicAdd(&s_sum[t][0], x);
        atomicAdd(&s_sum[t][1], y);
        atomicAdd(&s_sum[t][2], z);
        atomicAdd(&s_cnt[t], 1.f);
    }
    __syncthreads();

    if (tid < NC * 3) {
        int c = tid / 3, d = tid % 3;
        float v = ((float*)s_sum)[tid] / fmaxf(s_cnt[c], 1.f);
        s_cent[c][d] = v;
        cent_ws[(size_t)b * NC * 3 + tid] = v;
    }
    __syncthreads();

    // D[cp][c] = ||pred[b,cp] - cent_gt[b,c]||^2  (pred from [B,3,C] layout)
    if (tid < NC * NC) {
        int cp = tid / NC, c = tid % NC;
        float dx = cpred[(size_t)b * 3 * NC + 0 * NC + cp] - s_cent[c][0];
        float dy = cpred[(size_t)b * 3 * NC + 1 * NC + cp] - s_cent[c][1];
        float dz = cpred[(size_t)b * 3 * NC + 2 * NC + cp] - s_cent[c][2];
        s_D[cp][c] = dx * dx + dy * dy + dz * dz;
    }
    __syncthreads();

    if (tid < NC) {
        // l1 contribution: min over cp of D[cp][tid]
        float mn = s_D[0][tid];
        #pragma unroll
        for (int cp = 1; cp < NC; ++cp) mn = fminf(mn, s_D[cp][tid]);

        // l2 + separation for row cp = tid: two smallest of sqrt(D[tid][c])
        float m1 = 1e30f, m2 = 1e30f;
        #pragma unroll
        for (int c = 0; c < NC; ++c) {
            float d = sqrtf(s_D[tid][c]);
            if (d < m1) { m2 = m1; m1 = d; }
            else if (d < m2) { m2 = d; }
        }
        float contrib = mn + m1 * m1 + 0.1f * (m1 / m2);
        atomicAdd(&s_loss, contrib);
    }
    __syncthreads();
    if (tid == 0) atomicAdd(out, s_loss);
}

// Kernel B: per-point nearest-centroid distance + smooth-L1, block reduce,
// one atomicAdd per block.
__global__ void distance_loss_kernel(const float* __restrict__ disp, // [B,N]
                                     const float* __restrict__ sub,  // [B,3,N]
                                     const float* __restrict__ cent, // [B,C,3]
                                     float* __restrict__ out) {
    const int blocksPerBatch = NN / 256;           // 64
    const int b = blockIdx.x / blocksPerBatch;
    const int n = (blockIdx.x % blocksPerBatch) * 256 + threadIdx.x;

    __shared__ float s_cent[NC * 3];
    if (threadIdx.x < NC * 3)
        s_cent[threadIdx.x] = cent[(size_t)b * NC * 3 + threadIdx.x];
    __syncthreads();

    float x = sub[((size_t)b * 3 + 0) * NN + n];
    float y = sub[((size_t)b * 3 + 1) * NN + n];
    float z = sub[((size_t)b * 3 + 2) * NN + n];

    float mn = 1e30f;
    #pragma unroll
    for (int c = 0; c < NC; ++c) {
        float dx = x - s_cent[c * 3 + 0];
        float dy = y - s_cent[c * 3 + 1];
        float dz = z - s_cent[c * 3 + 2];
        mn = fminf(mn, dx * dx + dy * dy + dz * dz);
    }
    float dist = sqrtf(mn);
    float v = disp[(size_t)b * NN + n] - dist;
    float av = fabsf(v);
    float sm = (av < 1.f) ? 0.5f * v * v : (av - 0.5f);

    // wave (64-lane) shuffle reduce, then cross-wave via LDS
    #pragma unroll
    for (int o = 32; o > 0; o >>= 1) sm += __shfl_down(sm, o);

    __shared__ float s_part[4];
    const int wave = threadIdx.x >> 6;
    if ((threadIdx.x & 63) == 0) s_part[wave] = sm;
    __syncthreads();
    if (threadIdx.x == 0)
        atomicAdd(out, s_part[0] + s_part[1] + s_part[2] + s_part[3]);
}

extern "C" void kernel_launch(void* const* d_in, const int* in_sizes, int n_in,
                              void* d_out, int out_size, void* d_ws, size_t ws_size,
                              hipStream_t stream) {
    const float* disp   = (const float*)d_in[0]; // [B,N]
    const float* sub    = (const float*)d_in[1]; // [B,3,N]
    const float* cpred  = (const float*)d_in[2]; // [B,3,C]
    const float* origin = (const float*)d_in[3]; // [B,9,P]
    const int*   target = (const int*)d_in[4];   // [B,P]

    float* out     = (float*)d_out;
    float* cent_ws = (float*)d_ws;               // B*C*3 floats = 5376 B

    hipMemsetAsync(out, 0, sizeof(float), stream);
    centroids_chamfer_kernel<<<BB, 256, 0, stream>>>(origin, target, cpred, cent_ws, out);
    distance_loss_kernel<<<BB * (NN / 256), 256, 0, stream>>>(disp, sub, cent_ws, out);
}

// Round 2
// 93.200 us; speedup vs baseline: 1.2903x; 1.2903x over previous
//
#include <hip/hip_runtime.h>
#include <math.h>

#define NC 14        // classes / centroids
#define BB 32        // batch
#define NN 16384     // subsampled points per batch
#define PP 4096      // origin points per batch

// Kernel A: per-batch centroids (register-private predicated accumulation,
// NO atomics) -> ws, plus fused chamfer l1/l2 + separation -> atomicAdd(out).
__global__ void centroids_chamfer_kernel(const float* __restrict__ origin, // [B,9,P]
                                         const int*   __restrict__ target, // [B,P]
                                         const float* __restrict__ cpred,  // [B,3,C]
                                         float* __restrict__ cent_ws,      // [B,C,3]
                                         float* __restrict__ out) {
    const int b    = blockIdx.x;
    const int tid  = threadIdx.x;
    const int lane = tid & 63;
    const int wave = tid >> 6;

    // private accumulators: sums + count per class
    float sx[NC], sy[NC], sz[NC], sc[NC];
    #pragma unroll
    for (int c = 0; c < NC; ++c) { sx[c] = sy[c] = sz[c] = sc[c] = 0.f; }

    const float* ob = origin + (size_t)b * 9 * PP;
    const int*   tb = target + (size_t)b * PP;

    for (int p = tid; p < PP; p += 256) {
        int   t = tb[p];
        float x = ob[p], y = ob[PP + p], z = ob[2 * PP + p];
        #pragma unroll
        for (int c = 0; c < NC; ++c) {
            float m = (t == c) ? 1.f : 0.f;
            sx[c] = fmaf(m, x, sx[c]);
            sy[c] = fmaf(m, y, sy[c]);
            sz[c] = fmaf(m, z, sz[c]);
            sc[c] += m;
        }
    }

    // wave-level shuffle reduction (64 lanes)
    #pragma unroll
    for (int c = 0; c < NC; ++c) {
        #pragma unroll
        for (int o = 32; o > 0; o >>= 1) {
            sx[c] += __shfl_down(sx[c], o);
            sy[c] += __shfl_down(sy[c], o);
            sz[c] += __shfl_down(sz[c], o);
            sc[c] += __shfl_down(sc[c], o);
        }
    }

    __shared__ float s_part[4][NC][4];
    if (lane == 0) {
        #pragma unroll
        for (int c = 0; c < NC; ++c) {
            s_part[wave][c][0] = sx[c];
            s_part[wave][c][1] = sy[c];
            s_part[wave][c][2] = sz[c];
            s_part[wave][c][3] = sc[c];
        }
    }
    __syncthreads();

    __shared__ float s_cent[NC][3];
    if (tid < NC * 3) {
        int c = tid / 3, d = tid % 3;
        float s = s_part[0][c][d] + s_part[1][c][d] + s_part[2][c][d] + s_part[3][c][d];
        float n = s_part[0][c][3] + s_part[1][c][3] + s_part[2][c][3] + s_part[3][c][3];
        float v = s / fmaxf(n, 1.f);
        s_cent[c][d] = v;
        cent_ws[(size_t)b * NC * 3 + tid] = v;
    }
    __syncthreads();

    // D[cp][c] = ||pred[b,cp] - cent_gt[b,c]||^2  (pred from [B,3,C] layout)
    __shared__ float s_D[NC][NC];
    if (tid < NC * NC) {
        int cp = tid / NC, c = tid % NC;
        float dx = cpred[(size_t)b * 3 * NC + 0 * NC + cp] - s_cent[c][0];
        float dy = cpred[(size_t)b * 3 * NC + 1 * NC + cp] - s_cent[c][1];
        float dz = cpred[(size_t)b * 3 * NC + 2 * NC + cp] - s_cent[c][2];
        s_D[cp][c] = dx * dx + dy * dy + dz * dz;
    }
    __syncthreads();

    __shared__ float s_loss;
    if (tid == 0) s_loss = 0.f;
    __syncthreads();

    if (tid < NC) {
        // l1: min over cp of D[cp][tid]
        float mn = s_D[0][tid];
        #pragma unroll
        for (int cp = 1; cp < NC; ++cp) mn = fminf(mn, s_D[cp][tid]);

        // l2 + separation for row cp = tid: two smallest of sqrt(D[tid][c])
        float m1 = 1e30f, m2 = 1e30f;
        #pragma unroll
        for (int c = 0; c < NC; ++c) {
            float d = sqrtf(s_D[tid][c]);
            if (d < m1) { m2 = m1; m1 = d; }
            else if (d < m2) { m2 = d; }
        }
        float contrib = mn + m1 * m1 + 0.1f * (m1 / m2);
        atomicAdd(&s_loss, contrib);
    }
    __syncthreads();
    if (tid == 0) atomicAdd(out, s_loss);
}

// Kernel B: 4 points/thread via float4, nearest-centroid dist + smooth-L1,
// wave shuffle + LDS block reduce, one atomicAdd per block.
__global__ void distance_loss_kernel(const float* __restrict__ disp, // [B,N]
                                     const float* __restrict__ sub,  // [B,3,N]
                                     const float* __restrict__ cent, // [B,C,3]
                                     float* __restrict__ out) {
    const int blocksPerBatch = NN / 1024;          // 16
    const int b  = blockIdx.x / blocksPerBatch;
    const int n0 = (blockIdx.x % blocksPerBatch) * 1024 + threadIdx.x * 4;

    __shared__ float s_cent[NC * 3];
    if (threadIdx.x < NC * 3)
        s_cent[threadIdx.x] = cent[(size_t)b * NC * 3 + threadIdx.x];
    __syncthreads();

    const float4 xv = *(const float4*)&sub[((size_t)b * 3 + 0) * NN + n0];
    const float4 yv = *(const float4*)&sub[((size_t)b * 3 + 1) * NN + n0];
    const float4 zv = *(const float4*)&sub[((size_t)b * 3 + 2) * NN + n0];
    const float4 dv = *(const float4*)&disp[(size_t)b * NN + n0];

    const float xs[4] = {xv.x, xv.y, xv.z, xv.w};
    const float ys[4] = {yv.x, yv.y, yv.z, yv.w};
    const float zs[4] = {zv.x, zv.y, zv.z, zv.w};
    const float ds[4] = {dv.x, dv.y, dv.z, dv.w};

    float sm = 0.f;
    #pragma unroll
    for (int k = 0; k < 4; ++k) {
        float mn = 1e30f;
        #pragma unroll
        for (int c = 0; c < NC; ++c) {
            float dx = xs[k] - s_cent[c * 3 + 0];
            float dy = ys[k] - s_cent[c * 3 + 1];
            float dz = zs[k] - s_cent[c * 3 + 2];
            mn = fminf(mn, dx * dx + dy * dy + dz * dz);
        }
        float v  = ds[k] - sqrtf(mn);
        float av = fabsf(v);
        sm += (av < 1.f) ? 0.5f * v * v : (av - 0.5f);
    }

    #pragma unroll
    for (int o = 32; o > 0; o >>= 1) sm += __shfl_down(sm, o);

    __shared__ float s_part[4];
    const int wave = threadIdx.x >> 6;
    if ((threadIdx.x & 63) == 0) s_part[wave] = sm;
    __syncthreads();
    if (threadIdx.x == 0)
        atomicAdd(out, s_part[0] + s_part[1] + s_part[2] + s_part[3]);
}

extern "C" void kernel_launch(void* const* d_in, const int* in_sizes, int n_in,
                              void* d_out, int out_size, void* d_ws, size_t ws_size,
                              hipStream_t stream) {
    const float* disp   = (const float*)d_in[0]; // [B,N]
    const float* sub    = (const float*)d_in[1]; // [B,3,N]
    const float* cpred  = (const float*)d_in[2]; // [B,3,C]
    const float* origin = (const float*)d_in[3]; // [B,9,P]
    const int*   target = (const int*)d_in[4];   // [B,P]

    float* out     = (float*)d_out;
    float* cent_ws = (float*)d_ws;               // B*C*3 floats = 5376 B

    hipMemsetAsync(out, 0, sizeof(float), stream);
    centroids_chamfer_kernel<<<BB, 256, 0, stream>>>(origin, target, cpred, cent_ws, out);
    distance_loss_kernel<<<BB * (NN / 1024), 256, 0, stream>>>(disp, sub, cent_ws, out);
}